// Round 14
// baseline (205.447 us; speedup 1.0000x reference)
//
#include <hip/hip_runtime.h>
#include <hip/hip_bf16.h>

// ---------------------------------------------------------------------------
// R13: attn chunked 4-deep edge batching.
//   Evidence R7/R9/R12: wave retire rate pinned at ~480 waves/us regardless
//   of block shape -> per-wave critical path bound (~4 serial gather
//   latencies). Now group g owns a CONTIGUOUS quarter of the edge list and
//   processes 4 edges/chunk with all 8 loads issued up front (predicated
//   tail). Most nodes: 1 chunk -> 1-2 latencies per wave.
// GEMM (gload_lds), prep(+zero), CSR, pool unchanged from R12.
// ---------------------------------------------------------------------------

#define DEVFN static __device__ __forceinline__

typedef __attribute__((ext_vector_type(4))) float f32x4;
typedef __attribute__((ext_vector_type(2))) float f32x2;
typedef __attribute__((ext_vector_type(8))) short bf16x8;

#define GLOAD16(g, lds) __builtin_amdgcn_global_load_lds(                      \
    (const __attribute__((address_space(1))) unsigned int*)(g),                \
    (__attribute__((address_space(3))) unsigned int*)(lds), 16, 0, 0)

DEVFN float bfu2f(unsigned short u) {
    union { unsigned int i; float f; } t; t.i = ((unsigned)u) << 16; return t.f;
}
DEVFN unsigned short f2bu(float f) {
    __hip_bfloat16 b = __float2bfloat16(f);
    return __builtin_bit_cast(unsigned short, b);
}
DEVFN void stb4(__hip_bfloat16* p, float4 v) {
    ushort4 u;
    u.x = f2bu(v.x); u.y = f2bu(v.y); u.z = f2bu(v.z); u.w = f2bu(v.w);
    *reinterpret_cast<ushort4*>(p) = u;
}
DEVFN float4 f8x4_to_f4(unsigned u) {
    const f32x2 lo = __builtin_amdgcn_cvt_pk_f32_fp8((int)u, false);
    const f32x2 hi = __builtin_amdgcn_cvt_pk_f32_fp8((int)u, true);
    return make_float4(lo.x, lo.y, hi.x, hi.y);
}

// dot of q[16] with 16 fp8 values packed in uint4
DEVFN float dot16(const float* q, uint4 u) {
    const float4 f0 = f8x4_to_f4(u.x);
    const float4 f1 = f8x4_to_f4(u.y);
    const float4 f2 = f8x4_to_f4(u.z);
    const float4 f3 = f8x4_to_f4(u.w);
    float p;
    p = q[0] * f0.x;            p = fmaf(q[1],  f0.y, p);
    p = fmaf(q[2],  f0.z, p);   p = fmaf(q[3],  f0.w, p);
    p = fmaf(q[4],  f1.x, p);   p = fmaf(q[5],  f1.y, p);
    p = fmaf(q[6],  f1.z, p);   p = fmaf(q[7],  f1.w, p);
    p = fmaf(q[8],  f2.x, p);   p = fmaf(q[9],  f2.y, p);
    p = fmaf(q[10], f2.z, p);   p = fmaf(q[11], f2.w, p);
    p = fmaf(q[12], f3.x, p);   p = fmaf(q[13], f3.y, p);
    p = fmaf(q[14], f3.z, p);   p = fmaf(q[15], f3.w, p);
    return p;
}
// acc[16] += a * decode(u)
DEVFN void accum16(float* acc, uint4 u, float a) {
    const float4 f0 = f8x4_to_f4(u.x);
    const float4 f1 = f8x4_to_f4(u.y);
    const float4 f2 = f8x4_to_f4(u.z);
    const float4 f3 = f8x4_to_f4(u.w);
    acc[0]  = fmaf(a, f0.x, acc[0]);  acc[1]  = fmaf(a, f0.y, acc[1]);
    acc[2]  = fmaf(a, f0.z, acc[2]);  acc[3]  = fmaf(a, f0.w, acc[3]);
    acc[4]  = fmaf(a, f1.x, acc[4]);  acc[5]  = fmaf(a, f1.y, acc[5]);
    acc[6]  = fmaf(a, f1.z, acc[6]);  acc[7]  = fmaf(a, f1.w, acc[7]);
    acc[8]  = fmaf(a, f2.x, acc[8]);  acc[9]  = fmaf(a, f2.y, acc[9]);
    acc[10] = fmaf(a, f2.z, acc[10]); acc[11] = fmaf(a, f2.w, acc[11]);
    acc[12] = fmaf(a, f3.x, acc[12]); acc[13] = fmaf(a, f3.y, acc[13]);
    acc[14] = fmaf(a, f3.z, acc[14]); acc[15] = fmaf(a, f3.w, acc[15]);
}

// ----- fused prep: x->bf16 + weight transpose + zero the CSR int region -----
__global__ __launch_bounds__(256)
void prep_kernel(const float* __restrict__ x, __hip_bfloat16* __restrict__ xb, int nf2b,
                 const float* __restrict__ W0, const float* __restrict__ W1,
                 const float* __restrict__ W2, const float* __restrict__ W3,
                 const float* __restrict__ W4, const float* __restrict__ W5,
                 const float* __restrict__ W6, const float* __restrict__ W7,
                 __hip_bfloat16* __restrict__ Wt,
                 int4* __restrict__ zbase, int nz4)
{
    const int b = blockIdx.x;
    if (b < nf2b) {
        const int i = b * 256 + threadIdx.x;
        const float4 v = *reinterpret_cast<const float4*>(x + (size_t)i * 4);
        stb4(xb + (size_t)i * 4, v);
    } else if (b < nf2b + 2048) {
        const int wb = b - nf2b;       // 0..2047
        const int z  = wb >> 8;        // 0..7
        const int k  = wb & 255;       // 0..255
        const int c  = threadIdx.x;    // 0..255
        const float* W;
        switch (z) {
            case 0: W = W0; break; case 1: W = W1; break;
            case 2: W = W2; break; case 3: W = W3; break;
            case 4: W = W4; break; case 5: W = W5; break;
            case 6: W = W6; break; default: W = W7; break;
        }
        Wt[(size_t)z * 65536 + (size_t)c * 256 + k] =
            __float2bfloat16(W[(size_t)k * 256 + c]);
    } else {
        const int i = (b - nf2b - 2048) * 256 + threadIdx.x;
        if (i < nz4) zbase[i] = make_int4(0, 0, 0, 0);
    }
}

// ------------------------- GEMM: O[z] = A @ W[z] + b[z] ---------------------
#define SWZ64(r, kb) ((r) * 128 + ((kb) ^ (((r) & 7) << 4)))
#define TSTRIDE 272

__global__ __launch_bounds__(256)
void gemm_mfma_kernel(const __hip_bfloat16* __restrict__ A, int M,
                      const __hip_bfloat16* __restrict__ Wt,
                      const float* __restrict__ b0, const float* __restrict__ b1,
                      const float* __restrict__ b2, const float* __restrict__ b3,
                      void* __restrict__ O0, void* __restrict__ O1,
                      void* __restrict__ O2, void* __restrict__ O3,
                      int s0, int s1, int s2, int s3,
                      int f0, int f1, int f2, int f3)
{
    const int q8   = gridDim.x >> 3;
    const int wgid = (blockIdx.x & 7) * q8 + (blockIdx.x >> 3);
    const int rowblk = wgid >> 3;
    const int rem    = wgid & 7;
    const int colblk = rem >> 2;
    const int z      = rem & 3;

    const float* bias; void* O; int rs, isf8;
    switch (z) {
        case 0:  bias = b0; O = O0; rs = s0; isf8 = f0; break;
        case 1:  bias = b1; O = O1; rs = s1; isf8 = f1; break;
        case 2:  bias = b2; O = O2; rs = s2; isf8 = f2; break;
        default: bias = b3; O = O3; rs = s3; isf8 = f3; break;
    }
    const __hip_bfloat16* Wz = Wt + (size_t)z * 65536;

    __shared__ __align__(16) char Sh[128 * TSTRIDE];
    char* As = Sh;
    char* Bs = Sh + 16384;

    const int tid  = threadIdx.x;
    const int row0 = rowblk * 128;
    const int col0 = colblk * 128;
    const int wid  = tid >> 6, lane = tid & 63;
    const int wr   = wid >> 1, wc = wid & 1;
    const int lrow = lane & 15, kg = lane >> 4;

    f32x4 acc[4][4] = {};

    for (int k0 = 0; k0 < 256; k0 += 64) {
        #pragma unroll
        for (int j = 0; j < 4; ++j) {
            const int s_lin = j * 4096 + wid * 1024 + lane * 16;
            const int r     = s_lin >> 7;
            const int kb    = (s_lin & 127) ^ ((r & 7) << 4);
            const int kelem = k0 + (kb >> 1);
            char* ldsA = As + j * 4096 + wid * 1024;
            char* ldsB = Bs + j * 4096 + wid * 1024;
            const int gr = row0 + r;
            if (gr < M)
                GLOAD16(A + (size_t)gr * 256 + kelem, ldsA);
            GLOAD16(Wz + (size_t)(col0 + r) * 256 + kelem, ldsB);
        }
        __syncthreads();

        #pragma unroll
        for (int kk = 0; kk < 64; kk += 32) {
            const int kbyte = kk * 2 + kg * 16;
            bf16x8 af[4], bfr[4];
            #pragma unroll
            for (int m = 0; m < 4; ++m) {
                const int r = wr * 64 + m * 16 + lrow;
                af[m] = *reinterpret_cast<const bf16x8*>(As + SWZ64(r, kbyte));
            }
            #pragma unroll
            for (int n = 0; n < 4; ++n) {
                const int c = wc * 64 + n * 16 + lrow;
                bfr[n] = *reinterpret_cast<const bf16x8*>(Bs + SWZ64(c, kbyte));
            }
            #pragma unroll
            for (int m = 0; m < 4; ++m)
                #pragma unroll
                for (int n = 0; n < 4; ++n)
                    acc[m][n] = __builtin_amdgcn_mfma_f32_16x16x32_bf16(
                        af[m], bfr[n], acc[m][n], 0, 0, 0);
        }
        __syncthreads();
    }

    #pragma unroll
    for (int m = 0; m < 4; ++m) {
        #pragma unroll
        for (int j = 0; j < 4; ++j) {
            const int rr = wr * 64 + m * 16 + kg * 4 + j;
            #pragma unroll
            for (int n = 0; n < 4; ++n) {
                const int cc = wc * 64 + n * 16 + lrow;
                const float v = acc[m][n][j] + bias[col0 + cc];
                *reinterpret_cast<unsigned short*>(Sh + rr * TSTRIDE + cc * 2) = f2bu(v);
            }
        }
    }
    __syncthreads();

    const int row  = tid >> 1;
    const int half = tid & 1;
    const int grow = row0 + row;
    if (grow >= M) return;
    const char* src = Sh + row * TSTRIDE + half * 128;

    if (isf8) {
        unsigned char* dst = (unsigned char*)O + (size_t)grow * rs + col0 + half * 64;
        #pragma unroll
        for (int i2 = 0; i2 < 4; ++i2) {
            uint4 w;
            unsigned tmp[4];
            #pragma unroll
            for (int c8 = 0; c8 < 2; ++c8) {
                const bf16x8 e = *reinterpret_cast<const bf16x8*>(src + (i2 * 2 + c8) * 16);
                const int p0 = __builtin_amdgcn_cvt_pk_fp8_f32(
                    bfu2f((unsigned short)e[0]), bfu2f((unsigned short)e[1]), 0, false);
                const int p1 = __builtin_amdgcn_cvt_pk_fp8_f32(
                    bfu2f((unsigned short)e[2]), bfu2f((unsigned short)e[3]), 0, false);
                const int p2 = __builtin_amdgcn_cvt_pk_fp8_f32(
                    bfu2f((unsigned short)e[4]), bfu2f((unsigned short)e[5]), 0, false);
                const int p3 = __builtin_amdgcn_cvt_pk_fp8_f32(
                    bfu2f((unsigned short)e[6]), bfu2f((unsigned short)e[7]), 0, false);
                tmp[c8 * 2 + 0] = (unsigned)(p0 & 0xFFFF) | ((unsigned)(p1 & 0xFFFF) << 16);
                tmp[c8 * 2 + 1] = (unsigned)(p2 & 0xFFFF) | ((unsigned)(p3 & 0xFFFF) << 16);
            }
            w.x = tmp[0]; w.y = tmp[1]; w.z = tmp[2]; w.w = tmp[3];
            *reinterpret_cast<uint4*>(dst + i2 * 16) = w;
        }
    } else {
        char* dst = (char*)((__hip_bfloat16*)O + (size_t)grow * rs + col0 + half * 64);
        #pragma unroll
        for (int i = 0; i < 8; ++i)
            *reinterpret_cast<ulonglong2*>(dst + i * 16) =
                *reinterpret_cast<const ulonglong2*>(src + i * 16);
    }
}

// ------------------------------ CSR build ----------------------------------
__global__ __launch_bounds__(256)
void build_kernel(const int* __restrict__ ei, int E, int* __restrict__ deg, int nhist,
                  const int* __restrict__ batch, int N, int* __restrict__ gcount)
{
    if (blockIdx.x < nhist) {
        const int e = blockIdx.x * 256 + threadIdx.x;
        if (e < E) atomicAdd(&deg[ei[E + e]], 1);
    } else {
        __shared__ int h[16];
        if (threadIdx.x < 16) h[threadIdx.x] = 0;
        __syncthreads();
        const int n = (blockIdx.x - nhist) * 256 + threadIdx.x;
        if (n < N) atomicAdd(&h[batch[n]], 1);
        __syncthreads();
        if (threadIdx.x < 16 && h[threadIdx.x] != 0)
            atomicAdd(&gcount[threadIdx.x], h[threadIdx.x]);
    }
}

__global__ __launch_bounds__(1024)
void scan_kernel(const int* __restrict__ deg, int* __restrict__ row_start, int n,
                 const int* __restrict__ gcount, int* __restrict__ gstart)
{
    __shared__ int wsum[16];
    __shared__ int wincl[16];
    const int tid  = threadIdx.x;
    const int w    = tid >> 6;
    const int lane = tid & 63;
    if (tid == 0) {
        row_start[0] = 0;
        int o = 0;
        #pragma unroll
        for (int g = 0; g < 16; ++g) { gstart[g] = o; o += gcount[g]; }
        gstart[16] = o;
    }
    int offset = 0;
    for (int base = 0; base < n; base += 1024) {
        const int idx = base + tid;
        int s = (idx < n) ? deg[idx] : 0;
        #pragma unroll
        for (int d = 1; d < 64; d <<= 1) {
            const int t = __shfl_up(s, d, 64);
            if (lane >= d) s += t;
        }
        if (lane == 63) wsum[w] = s;
        __syncthreads();
        if (tid < 16) {
            int si = wsum[tid];
            #pragma unroll
            for (int d = 1; d < 16; d <<= 1) {
                const int u = __shfl_up(si, d, 64);
                if (tid >= d) si += u;
            }
            wincl[tid] = si;
        }
        __syncthreads();
        const int woff = (w > 0) ? wincl[w - 1] : 0;
        if (idx < n) row_start[idx + 1] = offset + woff + s;
        offset += wincl[15];
        __syncthreads();
    }
}

__global__ __launch_bounds__(256)
void fill_kernel(const int* __restrict__ ei, int E,
                 const int* __restrict__ row_start,
                 int* __restrict__ cursor, int* __restrict__ csr_src)
{
    const int e = blockIdx.x * 256 + threadIdx.x;
    if (e >= E) return;
    const int s = ei[e];
    const int d = ei[E + e];
    const int pos = atomicAdd(&cursor[d], 1);
    csr_src[row_start[d] + pos] = s;
}

// --------------------- fused attention + gate + layernorm ------------------
// 128 threads = 2 waves = 2 nodes. Lane = (group g = lane>>4, sublane s).
// Group g owns a CONTIGUOUS quarter of the edge list; 4 edges per chunk with
// all 8 KV loads issued before compute (predicated tail).
template <int NSH, bool RELU, bool OUTB>
__global__ __launch_bounds__(128)
void attn_kernel(const __hip_bfloat16* __restrict__ Q,
                 const unsigned char* __restrict__ KV,
                 const __hip_bfloat16* __restrict__ R,
                 const float* __restrict__ Wb, const float* __restrict__ lng,
                 const float* __restrict__ lnb,
                 const int* __restrict__ row_start, const int* __restrict__ csr_src,
                 __hip_bfloat16* __restrict__ outb, float* __restrict__ outf,
                 int N, float scale)
{
    const int wv   = threadIdx.x >> 6;
    const int lane = threadIdx.x & 63;
    const int g    = lane >> 4;
    const int s    = lane & 15;
    const int node = blockIdx.x * 2 + wv;
    if (node >= N) return;

    float q[16];
    {
        const bf16x8 a = *reinterpret_cast<const bf16x8*>(Q + (size_t)node * 256 + s * 16);
        const bf16x8 b = *reinterpret_cast<const bf16x8*>(Q + (size_t)node * 256 + s * 16 + 8);
        #pragma unroll
        for (int j = 0; j < 8; ++j) {
            q[j]     = bfu2f((unsigned short)a[j]);
            q[8 + j] = bfu2f((unsigned short)b[j]);
        }
    }

    const int beg = row_start[node];
    const int end = row_start[node + 1];
    const int deg = end - beg;
    const int per = (deg + 3) >> 2;            // edges per group (contiguous)
    const int i0  = beg + g * per;
    const int i1  = min(i0 + per, end);

    float acc[16] = {};
    float ssum = 0.f;

    for (int i = i0; i < i1; i += 4) {
        const int n  = i1 - i;                 // >= 1
        const int sa = csr_src[i];
        const int sb = csr_src[(n > 1) ? i + 1 : i];
        const int sc = csr_src[(n > 2) ? i + 2 : i];
        const int sd = csr_src[(n > 3) ? i + 3 : i];
        // issue all 8 loads before any compute
        const uint4 k0 = *reinterpret_cast<const uint4*>(KV + (size_t)sa * 512 + s * 16);
        const uint4 v0 = *reinterpret_cast<const uint4*>(KV + (size_t)sa * 512 + 256 + s * 16);
        const uint4 k1 = *reinterpret_cast<const uint4*>(KV + (size_t)sb * 512 + s * 16);
        const uint4 v1 = *reinterpret_cast<const uint4*>(KV + (size_t)sb * 512 + 256 + s * 16);
        const uint4 k2 = *reinterpret_cast<const uint4*>(KV + (size_t)sc * 512 + s * 16);
        const uint4 v2 = *reinterpret_cast<const uint4*>(KV + (size_t)sc * 512 + 256 + s * 16);
        const uint4 k3 = *reinterpret_cast<const uint4*>(KV + (size_t)sd * 512 + s * 16);
        const uint4 v3 = *reinterpret_cast<const uint4*>(KV + (size_t)sd * 512 + 256 + s * 16);
        float p0 = dot16(q, k0);
        float p1 = dot16(q, k1);
        float p2 = dot16(q, k2);
        float p3 = dot16(q, k3);
        #pragma unroll
        for (int m = 1; m < (1 << NSH); m <<= 1) {
            p0 += __shfl_xor(p0, m, 64);
            p1 += __shfl_xor(p1, m, 64);
            p2 += __shfl_xor(p2, m, 64);
            p3 += __shfl_xor(p3, m, 64);
        }
        const float a0 = __expf(p0 * scale);
        const float a1 = (n > 1) ? __expf(p1 * scale) : 0.f;
        const float a2 = (n > 2) ? __expf(p2 * scale) : 0.f;
        const float a3 = (n > 3) ? __expf(p3 * scale) : 0.f;
        ssum += (a0 + a1) + (a2 + a3);
        accum16(acc, v0, a0);
        accum16(acc, v1, a1);
        accum16(acc, v2, a2);
        accum16(acc, v3, a3);
    }

    // cross-group combine (sublane preserved by masks 16/32)
    ssum += __shfl_xor(ssum, 16, 64);
    ssum += __shfl_xor(ssum, 32, 64);
    #pragma unroll
    for (int j = 0; j < 16; ++j) {
        acc[j] += __shfl_xor(acc[j], 16, 64);
        acc[j] += __shfl_xor(acc[j], 32, 64);
    }

    if (g != 0) return;    // epilogue on group 0 only (holds all 256 dims)

    const float is = (ssum > 0.f) ? 1.f / ssum : 0.f;
    float o[16];
    #pragma unroll
    for (int j = 0; j < 16; ++j) o[j] = acc[j] * is;

    float r[16];
    {
        const bf16x8 a = *reinterpret_cast<const bf16x8*>(R + (size_t)node * 256 + s * 16);
        const bf16x8 b = *reinterpret_cast<const bf16x8*>(R + (size_t)node * 256 + s * 16 + 8);
        #pragma unroll
        for (int j = 0; j < 8; ++j) {
            r[j]     = bfu2f((unsigned short)a[j]);
            r[8 + j] = bfu2f((unsigned short)b[j]);
        }
    }

    float z = 0.f;
    #pragma unroll
    for (int j = 0; j < 16; ++j) {
        const int d = s * 16 + j;
        z += o[j] * Wb[d] + r[j] * Wb[256 + d] + (o[j] - r[j]) * Wb[512 + d];
    }
    #pragma unroll
    for (int m = 1; m < 16; m <<= 1) z += __shfl_xor(z, m, 64);
    const float gg = 1.f / (1.f + __expf(-z));

    float h[16];
    float s1 = 0.f, s2 = 0.f;
    #pragma unroll
    for (int j = 0; j < 16; ++j) {
        h[j] = gg * r[j] + (1.f - gg) * o[j];
        s1 += h[j];
        s2 += h[j] * h[j];
    }
    #pragma unroll
    for (int m = 1; m < 16; m <<= 1) {
        s1 += __shfl_xor(s1, m, 64);
        s2 += __shfl_xor(s2, m, 64);
    }
    const float mu  = s1 * (1.f / 256.f);
    const float var = s2 * (1.f / 256.f) - mu * mu;
    const float inv = rsqrtf(var + 1e-5f);

    #pragma unroll
    for (int j = 0; j < 16; ++j) {
        const int d = s * 16 + j;
        h[j] = (h[j] - mu) * inv * lng[d] + lnb[d];
        if (RELU) h[j] = fmaxf(h[j], 0.f);
    }

    if (OUTB) {
        __hip_bfloat16* dst = outb + (size_t)node * 256 + s * 16;
        stb4(dst,      make_float4(h[0],  h[1],  h[2],  h[3]));
        stb4(dst + 4,  make_float4(h[4],  h[5],  h[6],  h[7]));
        stb4(dst + 8,  make_float4(h[8],  h[9],  h[10], h[11]));
        stb4(dst + 12, make_float4(h[12], h[13], h[14], h[15]));
    } else {
        float* dst = outf + (size_t)node * 256 + s * 16;
        #pragma unroll
        for (int c4 = 0; c4 < 4; ++c4)
            *reinterpret_cast<float4*>(dst + c4 * 4) =
                make_float4(h[c4 * 4], h[c4 * 4 + 1], h[c4 * 4 + 2], h[c4 * 4 + 3]);
    }
}

// ------------------------------ mean pool (two-stage) ----------------------
__global__ __launch_bounds__(256)
void pool_partial_kernel(const float* __restrict__ h, const int* __restrict__ gstart,
                         float* __restrict__ partial)
{
    const int s    = blockIdx.x;
    const int g    = blockIdx.y;
    const int tid  = threadIdx.x;
    const int quad = tid & 63;
    const int sub  = tid >> 6;

    const int beg = gstart[g];
    const int cnt = gstart[g + 1] - beg;

    f32x4 acc = {0.f, 0.f, 0.f, 0.f};
    for (int i = s * 4 + sub; i < cnt; i += 64) {
        const f32x4 v = *reinterpret_cast<const f32x4*>(
            h + (size_t)(beg + i) * 256 + quad * 4);
        acc += v;
    }

    __shared__ f32x4 sh[4][64];
    sh[sub][quad] = acc;
    __syncthreads();
    if (sub == 0) {
        const f32x4 r = sh[0][quad] + sh[1][quad] + sh[2][quad] + sh[3][quad];
        *reinterpret_cast<f32x4*>(partial + ((size_t)(g * 16 + s) * 64 + quad) * 4) = r;
    }
}

__global__ __launch_bounds__(256)
void pool_final_kernel(const float* __restrict__ partial, const int* __restrict__ gcount,
                       float* __restrict__ out)
{
    const int g = blockIdx.x;
    const int d = threadIdx.x;
    float sum = 0.f;
    #pragma unroll
    for (int s = 0; s < 16; ++s)
        sum += partial[(size_t)(g * 16 + s) * 256 + d];
    out[(size_t)g * 256 + d] = sum / (float)max(gcount[g], 1);
}

// ------------------------------- launcher ----------------------------------
extern "C" void kernel_launch(void* const* d_in, const int* in_sizes, int n_in,
                              void* d_out, int out_size, void* d_ws, size_t ws_size,
                              hipStream_t stream)
{
    const float* x     = (const float*)d_in[0];
    const int*   ei    = (const int*)d_in[1];
    const int*   batch = (const int*)d_in[2];
    const float* Wq0 = (const float*)d_in[3];  const float* bq0 = (const float*)d_in[4];
    const float* Wk0 = (const float*)d_in[5];  const float* bk0 = (const float*)d_in[6];
    const float* Wv0 = (const float*)d_in[7];  const float* bv0 = (const float*)d_in[8];
    const float* Ws0 = (const float*)d_in[9];  const float* bs0 = (const float*)d_in[10];
    const float* Wb0 = (const float*)d_in[11];
    const float* g0  = (const float*)d_in[12]; const float* b0  = (const float*)d_in[13];
    const float* Wq1 = (const float*)d_in[14]; const float* bq1 = (const float*)d_in[15];
    const float* Wk1 = (const float*)d_in[16]; const float* bk1 = (const float*)d_in[17];
    const float* Wv1 = (const float*)d_in[18]; const float* bv1 = (const float*)d_in[19];
    const float* Ws1 = (const float*)d_in[20]; const float* bs1 = (const float*)d_in[21];
    const float* Wb1 = (const float*)d_in[22];
    const float* g1  = (const float*)d_in[23]; const float* b1  = (const float*)d_in[24];

    const int N = in_sizes[0] / 256;
    const int E = in_sizes[1] / 2;
    const int G = 16;
    const size_t NM = (size_t)N * 256;

    __hip_bfloat16* bws = (__hip_bfloat16*)d_ws;
    __hip_bfloat16* xb  = bws;
    __hip_bfloat16* qb  = xb  + NM;
    __hip_bfloat16* rb  = qb  + NM;
    __hip_bfloat16* h0b = rb  + NM;
    __hip_bfloat16* wt  = h0b + NM;               // 8 * 65536 bf16
    unsigned char* kvb  = (unsigned char*)(wt + 8 * 65536);   // [N][512] fp8
    float* h1f     = (float*)(kvb + (size_t)N * 512);
    float* partial = h1f + NM;                    // 16*16*256 f32
    int* deg       = (int*)(partial + 16 * 16 * 256);
    int* row_start = deg + N;
    int* cursor    = row_start + N + 1;
    int* gcount    = cursor + N;
    int* gstart    = gcount + G;                  // 17
    int* csr_src   = gstart + 17;

    const int eb = (E + 255) / 256;
    const int nb = (N + 255) / 256;
    const int nf2b = (int)((NM / 4 + 255) / 256);

    const int zwords = 3 * N + G + 18;
    const int nz4    = (zwords + 3) / 4;
    const int nzb    = (nz4 + 255) / 256;

    prep_kernel<<<nf2b + 2048 + nzb, 256, 0, stream>>>(x, xb, nf2b,
        Wq0, Wk0, Wv0, Ws0, Wq1, Wk1, Wv1, Ws1, wt,
        (int4*)deg, nz4);

    build_kernel<<<eb + nb, 256, 0, stream>>>(ei, E, deg, eb, batch, N, gcount);
    scan_kernel<<<1, 1024, 0, stream>>>(deg, row_start, N, gcount, gstart);
    fill_kernel<<<eb, 256, 0, stream>>>(ei, E, row_start, cursor, csr_src);

    const int nrb   = (N + 127) / 128;
    const int ggrid = nrb * 8;
    const int agrid = (N + 1) / 2;

    // layer 0
    gemm_mfma_kernel<<<ggrid, 256, 0, stream>>>(xb, N, wt,
        bq0, bk0, bv0, bs0,
        qb, kvb, kvb + 256, rb,
        256, 512, 512, 256,
        0, 1, 1, 0);
    attn_kernel<2, true, true><<<agrid, 128, 0, stream>>>(
        qb, kvb, rb, Wb0, g0, b0, row_start, csr_src, h0b, nullptr, N, 0.125f);

    // layer 1
    gemm_mfma_kernel<<<ggrid, 256, 0, stream>>>(h0b, N, wt + 4 * 65536,
        bq1, bk1, bv1, bs1,
        qb, kvb, kvb + 256, rb,
        256, 512, 512, 256,
        0, 1, 1, 0);
    attn_kernel<4, false, false><<<agrid, 128, 0, stream>>>(
        qb, kvb, rb, Wb1, g1, b1, row_start, csr_src, nullptr, h1f, N, 0.0625f);

    pool_partial_kernel<<<dim3(16, 16), 256, 0, stream>>>(h1f, gstart, partial);
    pool_final_kernel<<<16, 256, 0, stream>>>(partial, gcount, (float*)d_out);
}

// Round 15
// 195.649 us; speedup vs baseline: 1.0501x; 1.0501x over previous
//
#include <hip/hip_runtime.h>
#include <hip/hip_bf16.h>

// ---------------------------------------------------------------------------
// R14: GEMM 2-phase software pipeline (T3/T4-lite) + attn reverted to R12.
//   R13 post-mortem: 3rd null attn experiment; attn floored ~41.6us at the
//   random-gather ceiling (160MB/layer @ ~4.5TB/s L2-mixed). Revert to R12.
//   GEMM: double-buffered gload_lds staging; issue next tile BEFORE compute,
//   counted asm vmcnt(8) + raw s_barrier (loads stay in flight across the
//   barrier — the documented m97-ceiling fix). OOB rows clamped so every
//   wave issues exactly 8 vmem ops (vmcnt ledger exact).
//   fill_kernel merged into gemm0 grid (saves dispatch, overlaps atomics).
// ---------------------------------------------------------------------------

#define DEVFN static __device__ __forceinline__

typedef __attribute__((ext_vector_type(4))) float f32x4;
typedef __attribute__((ext_vector_type(2))) float f32x2;
typedef __attribute__((ext_vector_type(8))) short bf16x8;

#define GLOAD16(g, lds) __builtin_amdgcn_global_load_lds(                      \
    (const __attribute__((address_space(1))) unsigned int*)(g),                \
    (__attribute__((address_space(3))) unsigned int*)(lds), 16, 0, 0)

DEVFN float bfu2f(unsigned short u) {
    union { unsigned int i; float f; } t; t.i = ((unsigned)u) << 16; return t.f;
}
DEVFN unsigned short f2bu(float f) {
    __hip_bfloat16 b = __float2bfloat16(f);
    return __builtin_bit_cast(unsigned short, b);
}
DEVFN void stb4(__hip_bfloat16* p, float4 v) {
    ushort4 u;
    u.x = f2bu(v.x); u.y = f2bu(v.y); u.z = f2bu(v.z); u.w = f2bu(v.w);
    *reinterpret_cast<ushort4*>(p) = u;
}
DEVFN float4 f8x4_to_f4(unsigned u) {
    const f32x2 lo = __builtin_amdgcn_cvt_pk_f32_fp8((int)u, false);
    const f32x2 hi = __builtin_amdgcn_cvt_pk_f32_fp8((int)u, true);
    return make_float4(lo.x, lo.y, hi.x, hi.y);
}

DEVFN float dot16(const float* q, uint4 u) {
    const float4 f0 = f8x4_to_f4(u.x);
    const float4 f1 = f8x4_to_f4(u.y);
    const float4 f2 = f8x4_to_f4(u.z);
    const float4 f3 = f8x4_to_f4(u.w);
    float p;
    p = q[0] * f0.x;            p = fmaf(q[1],  f0.y, p);
    p = fmaf(q[2],  f0.z, p);   p = fmaf(q[3],  f0.w, p);
    p = fmaf(q[4],  f1.x, p);   p = fmaf(q[5],  f1.y, p);
    p = fmaf(q[6],  f1.z, p);   p = fmaf(q[7],  f1.w, p);
    p = fmaf(q[8],  f2.x, p);   p = fmaf(q[9],  f2.y, p);
    p = fmaf(q[10], f2.z, p);   p = fmaf(q[11], f2.w, p);
    p = fmaf(q[12], f3.x, p);   p = fmaf(q[13], f3.y, p);
    p = fmaf(q[14], f3.z, p);   p = fmaf(q[15], f3.w, p);
    return p;
}
DEVFN void accum16(float* acc, uint4 u, float a) {
    const float4 f0 = f8x4_to_f4(u.x);
    const float4 f1 = f8x4_to_f4(u.y);
    const float4 f2 = f8x4_to_f4(u.z);
    const float4 f3 = f8x4_to_f4(u.w);
    acc[0]  = fmaf(a, f0.x, acc[0]);  acc[1]  = fmaf(a, f0.y, acc[1]);
    acc[2]  = fmaf(a, f0.z, acc[2]);  acc[3]  = fmaf(a, f0.w, acc[3]);
    acc[4]  = fmaf(a, f1.x, acc[4]);  acc[5]  = fmaf(a, f1.y, acc[5]);
    acc[6]  = fmaf(a, f1.z, acc[6]);  acc[7]  = fmaf(a, f1.w, acc[7]);
    acc[8]  = fmaf(a, f2.x, acc[8]);  acc[9]  = fmaf(a, f2.y, acc[9]);
    acc[10] = fmaf(a, f2.z, acc[10]); acc[11] = fmaf(a, f2.w, acc[11]);
    acc[12] = fmaf(a, f3.x, acc[12]); acc[13] = fmaf(a, f3.y, acc[13]);
    acc[14] = fmaf(a, f3.z, acc[14]); acc[15] = fmaf(a, f3.w, acc[15]);
}

// ----- fused prep: x->bf16 + weight transpose + zero the CSR int region -----
__global__ __launch_bounds__(256)
void prep_kernel(const float* __restrict__ x, __hip_bfloat16* __restrict__ xb, int nf2b,
                 const float* __restrict__ W0, const float* __restrict__ W1,
                 const float* __restrict__ W2, const float* __restrict__ W3,
                 const float* __restrict__ W4, const float* __restrict__ W5,
                 const float* __restrict__ W6, const float* __restrict__ W7,
                 __hip_bfloat16* __restrict__ Wt,
                 int4* __restrict__ zbase, int nz4)
{
    const int b = blockIdx.x;
    if (b < nf2b) {
        const int i = b * 256 + threadIdx.x;
        const float4 v = *reinterpret_cast<const float4*>(x + (size_t)i * 4);
        stb4(xb + (size_t)i * 4, v);
    } else if (b < nf2b + 2048) {
        const int wb = b - nf2b;
        const int z  = wb >> 8;
        const int k  = wb & 255;
        const int c  = threadIdx.x;
        const float* W;
        switch (z) {
            case 0: W = W0; break; case 1: W = W1; break;
            case 2: W = W2; break; case 3: W = W3; break;
            case 4: W = W4; break; case 5: W = W5; break;
            case 6: W = W6; break; default: W = W7; break;
        }
        Wt[(size_t)z * 65536 + (size_t)c * 256 + k] =
            __float2bfloat16(W[(size_t)k * 256 + c]);
    } else {
        const int i = (b - nf2b - 2048) * 256 + threadIdx.x;
        if (i < nz4) zbase[i] = make_int4(0, 0, 0, 0);
    }
}

// ------------------------- GEMM: O[z] = A @ W[z] + b[z] ---------------------
// BK=64, 2-phase pipelined gload_lds staging (double buffer), counted vmcnt.
// Extra blocks past ngemm run fill_kernel logic (layer-0 call only).
#define SWZ64(r, kb) ((r) * 128 + ((kb) ^ (((r) & 7) << 4)))
#define TSTRIDE 272

__global__ __launch_bounds__(256)
void gemm_mfma_kernel(const __hip_bfloat16* __restrict__ A, int M,
                      const __hip_bfloat16* __restrict__ Wt,
                      const float* __restrict__ b0, const float* __restrict__ b1,
                      const float* __restrict__ b2, const float* __restrict__ b3,
                      void* __restrict__ O0, void* __restrict__ O1,
                      void* __restrict__ O2, void* __restrict__ O3,
                      int s0, int s1, int s2, int s3,
                      int f0, int f1, int f2, int f3,
                      int ngemm,
                      const int* __restrict__ ei, int E, int efill,
                      const int* __restrict__ row_start,
                      int* __restrict__ cursor, int* __restrict__ csr_src)
{
    __shared__ __align__(16) char Sh[65536];   // As0|Bs0|As1|Bs1 (4x16KB)

    if ((int)blockIdx.x >= ngemm) {
        // ---- merged fill_kernel blocks ----
        const int e = ((int)blockIdx.x - ngemm) * 256 + threadIdx.x;
        if (e < efill) {
            const int s = ei[e];
            const int d = ei[E + e];
            const int pos = atomicAdd(&cursor[d], 1);
            csr_src[row_start[d] + pos] = s;
        }
        return;
    }

    // bijective XCD swizzle over the gemm range (ngemm % 8 == 0)
    const int q8   = ngemm >> 3;
    const int wgid = ((int)blockIdx.x & 7) * q8 + ((int)blockIdx.x >> 3);
    const int rowblk = wgid >> 3;
    const int rem    = wgid & 7;
    const int colblk = rem >> 2;
    const int z      = rem & 3;

    const float* bias; void* O; int rs, isf8;
    switch (z) {
        case 0:  bias = b0; O = O0; rs = s0; isf8 = f0; break;
        case 1:  bias = b1; O = O1; rs = s1; isf8 = f1; break;
        case 2:  bias = b2; O = O2; rs = s2; isf8 = f2; break;
        default: bias = b3; O = O3; rs = s3; isf8 = f3; break;
    }
    const __hip_bfloat16* Wz = Wt + (size_t)z * 65536;

    char* AsB[2] = {Sh,         Sh + 32768};
    char* BsB[2] = {Sh + 16384, Sh + 49152};

    const int tid  = threadIdx.x;
    const int row0 = rowblk * 128;
    const int col0 = colblk * 128;
    const int wid  = tid >> 6, lane = tid & 63;
    const int wr   = wid >> 1, wc = wid & 1;
    const int lrow = lane & 15, kg = lane >> 4;

    f32x4 acc[4][4] = {};

    // stage tile t into buffer buf: exactly 8 vmem instrs per wave
    // (OOB rows clamped, not predicated, so the vmcnt ledger is exact).
#define STAGE(buf, k0)                                                        \
    {                                                                         \
        _Pragma("unroll")                                                     \
        for (int j = 0; j < 4; ++j) {                                         \
            const int s_lin = j * 4096 + wid * 1024 + lane * 16;              \
            const int r     = s_lin >> 7;                                     \
            const int kb    = (s_lin & 127) ^ ((r & 7) << 4);                 \
            const int kelem = (k0) + (kb >> 1);                               \
            char* ldsA = AsB[buf] + j * 4096 + wid * 1024;                    \
            char* ldsB = BsB[buf] + j * 4096 + wid * 1024;                    \
            const int gr = min(row0 + r, M - 1);                              \
            GLOAD16(A + (size_t)gr * 256 + kelem, ldsA);                      \
            GLOAD16(Wz + (size_t)(col0 + r) * 256 + kelem, ldsB);             \
        }                                                                     \
    }

    STAGE(0, 0);

    #pragma unroll
    for (int t = 0; t < 4; ++t) {
        const int cur = t & 1;
        if (t < 3) {
            STAGE(cur ^ 1, (t + 1) * 64);
            asm volatile("s_waitcnt vmcnt(8)" ::: "memory");
        } else {
            asm volatile("s_waitcnt vmcnt(0)" ::: "memory");
        }
        __builtin_amdgcn_sched_barrier(0);
        __builtin_amdgcn_s_barrier();      // all waves: tile t resident
        __builtin_amdgcn_sched_barrier(0);

        const char* As = AsB[cur];
        const char* Bs = BsB[cur];
        #pragma unroll
        for (int kk = 0; kk < 64; kk += 32) {
            const int kbyte = kk * 2 + kg * 16;
            bf16x8 af[4], bfr[4];
            #pragma unroll
            for (int m = 0; m < 4; ++m) {
                const int r = wr * 64 + m * 16 + lrow;
                af[m] = *reinterpret_cast<const bf16x8*>(As + SWZ64(r, kbyte));
            }
            #pragma unroll
            for (int n = 0; n < 4; ++n) {
                const int c = wc * 64 + n * 16 + lrow;
                bfr[n] = *reinterpret_cast<const bf16x8*>(Bs + SWZ64(c, kbyte));
            }
            #pragma unroll
            for (int m = 0; m < 4; ++m)
                #pragma unroll
                for (int n = 0; n < 4; ++n)
                    acc[m][n] = __builtin_amdgcn_mfma_f32_16x16x32_bf16(
                        af[m], bfr[n], acc[m][n], 0, 0, 0);
        }
        asm volatile("s_waitcnt lgkmcnt(0)" ::: "memory");
        __builtin_amdgcn_sched_barrier(0);
        __builtin_amdgcn_s_barrier();      // tile t fully consumed; buf free
        __builtin_amdgcn_sched_barrier(0);
    }
#undef STAGE

    // ---- epilogue: stage bf16 tile in LDS (stride 272B) ----
    #pragma unroll
    for (int m = 0; m < 4; ++m) {
        #pragma unroll
        for (int j = 0; j < 4; ++j) {
            const int rr = wr * 64 + m * 16 + kg * 4 + j;
            #pragma unroll
            for (int n = 0; n < 4; ++n) {
                const int cc = wc * 64 + n * 16 + lrow;
                const float v = acc[m][n][j] + bias[col0 + cc];
                *reinterpret_cast<unsigned short*>(Sh + rr * TSTRIDE + cc * 2) = f2bu(v);
            }
        }
    }
    __syncthreads();

    const int row  = tid >> 1;
    const int half = tid & 1;
    const int grow = row0 + row;
    if (grow >= M) return;
    const char* src = Sh + row * TSTRIDE + half * 128;

    if (isf8) {
        unsigned char* dst = (unsigned char*)O + (size_t)grow * rs + col0 + half * 64;
        #pragma unroll
        for (int i2 = 0; i2 < 4; ++i2) {
            uint4 w;
            unsigned tmp[4];
            #pragma unroll
            for (int c8 = 0; c8 < 2; ++c8) {
                const bf16x8 e = *reinterpret_cast<const bf16x8*>(src + (i2 * 2 + c8) * 16);
                const int p0 = __builtin_amdgcn_cvt_pk_fp8_f32(
                    bfu2f((unsigned short)e[0]), bfu2f((unsigned short)e[1]), 0, false);
                const int p1 = __builtin_amdgcn_cvt_pk_fp8_f32(
                    bfu2f((unsigned short)e[2]), bfu2f((unsigned short)e[3]), 0, false);
                const int p2 = __builtin_amdgcn_cvt_pk_fp8_f32(
                    bfu2f((unsigned short)e[4]), bfu2f((unsigned short)e[5]), 0, false);
                const int p3 = __builtin_amdgcn_cvt_pk_fp8_f32(
                    bfu2f((unsigned short)e[6]), bfu2f((unsigned short)e[7]), 0, false);
                tmp[c8 * 2 + 0] = (unsigned)(p0 & 0xFFFF) | ((unsigned)(p1 & 0xFFFF) << 16);
                tmp[c8 * 2 + 1] = (unsigned)(p2 & 0xFFFF) | ((unsigned)(p3 & 0xFFFF) << 16);
            }
            w.x = tmp[0]; w.y = tmp[1]; w.z = tmp[2]; w.w = tmp[3];
            *reinterpret_cast<uint4*>(dst + i2 * 16) = w;
        }
    } else {
        char* dst = (char*)((__hip_bfloat16*)O + (size_t)grow * rs + col0 + half * 64);
        #pragma unroll
        for (int i = 0; i < 8; ++i)
            *reinterpret_cast<ulonglong2*>(dst + i * 16) =
                *reinterpret_cast<const ulonglong2*>(src + i * 16);
    }
}

// ------------------------------ CSR build ----------------------------------
__global__ __launch_bounds__(256)
void build_kernel(const int* __restrict__ ei, int E, int* __restrict__ deg, int nhist,
                  const int* __restrict__ batch, int N, int* __restrict__ gcount)
{
    if (blockIdx.x < nhist) {
        const int e = blockIdx.x * 256 + threadIdx.x;
        if (e < E) atomicAdd(&deg[ei[E + e]], 1);
    } else {
        __shared__ int h[16];
        if (threadIdx.x < 16) h[threadIdx.x] = 0;
        __syncthreads();
        const int n = (blockIdx.x - nhist) * 256 + threadIdx.x;
        if (n < N) atomicAdd(&h[batch[n]], 1);
        __syncthreads();
        if (threadIdx.x < 16 && h[threadIdx.x] != 0)
            atomicAdd(&gcount[threadIdx.x], h[threadIdx.x]);
    }
}

__global__ __launch_bounds__(1024)
void scan_kernel(const int* __restrict__ deg, int* __restrict__ row_start, int n,
                 const int* __restrict__ gcount, int* __restrict__ gstart)
{
    __shared__ int wsum[16];
    __shared__ int wincl[16];
    const int tid  = threadIdx.x;
    const int w    = tid >> 6;
    const int lane = tid & 63;
    if (tid == 0) {
        row_start[0] = 0;
        int o = 0;
        #pragma unroll
        for (int g = 0; g < 16; ++g) { gstart[g] = o; o += gcount[g]; }
        gstart[16] = o;
    }
    int offset = 0;
    for (int base = 0; base < n; base += 1024) {
        const int idx = base + tid;
        int s = (idx < n) ? deg[idx] : 0;
        #pragma unroll
        for (int d = 1; d < 64; d <<= 1) {
            const int t = __shfl_up(s, d, 64);
            if (lane >= d) s += t;
        }
        if (lane == 63) wsum[w] = s;
        __syncthreads();
        if (tid < 16) {
            int si = wsum[tid];
            #pragma unroll
            for (int d = 1; d < 16; d <<= 1) {
                const int u = __shfl_up(si, d, 64);
                if (tid >= d) si += u;
            }
            wincl[tid] = si;
        }
        __syncthreads();
        const int woff = (w > 0) ? wincl[w - 1] : 0;
        if (idx < n) row_start[idx + 1] = offset + woff + s;
        offset += wincl[15];
        __syncthreads();
    }
}

// --------------------- fused attention + gate + layernorm ------------------
// R12's exact form (best measured): 128 threads = 2 waves = 2 nodes;
// 16-lane groups, strided edges, 2-deep unroll.
template <int NSH, bool RELU, bool OUTB>
__global__ __launch_bounds__(128)
void attn_kernel(const __hip_bfloat16* __restrict__ Q,
                 const unsigned char* __restrict__ KV,
                 const __hip_bfloat16* __restrict__ R,
                 const float* __restrict__ Wb, const float* __restrict__ lng,
                 const float* __restrict__ lnb,
                 const int* __restrict__ row_start, const int* __restrict__ csr_src,
                 __hip_bfloat16* __restrict__ outb, float* __restrict__ outf,
                 int N, float scale)
{
    const int wv   = threadIdx.x >> 6;
    const int lane = threadIdx.x & 63;
    const int g    = lane >> 4;
    const int s    = lane & 15;
    const int node = blockIdx.x * 2 + wv;
    if (node >= N) return;

    float q[16];
    {
        const bf16x8 a = *reinterpret_cast<const bf16x8*>(Q + (size_t)node * 256 + s * 16);
        const bf16x8 b = *reinterpret_cast<const bf16x8*>(Q + (size_t)node * 256 + s * 16 + 8);
        #pragma unroll
        for (int j = 0; j < 8; ++j) {
            q[j]     = bfu2f((unsigned short)a[j]);
            q[8 + j] = bfu2f((unsigned short)b[j]);
        }
    }

    const int beg = row_start[node];
    const int end = row_start[node + 1];

    float acc[16] = {};
    float ssum = 0.f;

    int i = beg + g;
    for (; i + 4 < end; i += 8) {
        const int sa = csr_src[i];
        const int sb = csr_src[i + 4];
        const uint4 ka = *reinterpret_cast<const uint4*>(KV + (size_t)sa * 512 + s * 16);
        const uint4 va = *reinterpret_cast<const uint4*>(KV + (size_t)sa * 512 + 256 + s * 16);
        const uint4 kb = *reinterpret_cast<const uint4*>(KV + (size_t)sb * 512 + s * 16);
        const uint4 vb = *reinterpret_cast<const uint4*>(KV + (size_t)sb * 512 + 256 + s * 16);
        float pa = dot16(q, ka);
        float pb = dot16(q, kb);
        #pragma unroll
        for (int m = 1; m < (1 << NSH); m <<= 1) {
            pa += __shfl_xor(pa, m, 64);
            pb += __shfl_xor(pb, m, 64);
        }
        const float aa = __expf(pa * scale);
        const float ab = __expf(pb * scale);
        ssum += aa + ab;
        accum16(acc, va, aa);
        accum16(acc, vb, ab);
    }
    if (i < end) {
        const int sa = csr_src[i];
        const uint4 ka = *reinterpret_cast<const uint4*>(KV + (size_t)sa * 512 + s * 16);
        const uint4 va = *reinterpret_cast<const uint4*>(KV + (size_t)sa * 512 + 256 + s * 16);
        float pa = dot16(q, ka);
        #pragma unroll
        for (int m = 1; m < (1 << NSH); m <<= 1) pa += __shfl_xor(pa, m, 64);
        const float aa = __expf(pa * scale);
        ssum += aa;
        accum16(acc, va, aa);
    }

    ssum += __shfl_xor(ssum, 16, 64);
    ssum += __shfl_xor(ssum, 32, 64);
    #pragma unroll
    for (int j = 0; j < 16; ++j) {
        acc[j] += __shfl_xor(acc[j], 16, 64);
        acc[j] += __shfl_xor(acc[j], 32, 64);
    }

    if (g != 0) return;

    const float is = (ssum > 0.f) ? 1.f / ssum : 0.f;
    float o[16];
    #pragma unroll
    for (int j = 0; j < 16; ++j) o[j] = acc[j] * is;

    float r[16];
    {
        const bf16x8 a = *reinterpret_cast<const bf16x8*>(R + (size_t)node * 256 + s * 16);
        const bf16x8 b = *reinterpret_cast<const bf16x8*>(R + (size_t)node * 256 + s * 16 + 8);
        #pragma unroll
        for (int j = 0; j < 8; ++j) {
            r[j]     = bfu2f((unsigned short)a[j]);
            r[8 + j] = bfu2f((unsigned short)b[j]);
        }
    }

    float z = 0.f;
    #pragma unroll
    for (int j = 0; j < 16; ++j) {
        const int d = s * 16 + j;
        z += o[j] * Wb[d] + r[j] * Wb[256 + d] + (o[j] - r[j]) * Wb[512 + d];
    }
    #pragma unroll
    for (int m = 1; m < 16; m <<= 1) z += __shfl_xor(z, m, 64);
    const float gg = 1.f / (1.f + __expf(-z));

    float h[16];
    float s1 = 0.f, s2 = 0.f;
    #pragma unroll
    for (int j = 0; j < 16; ++j) {
        h[j] = gg * r[j] + (1.f - gg) * o[j];
        s1 += h[j];
        s2 += h[j] * h[j];
    }
    #pragma unroll
    for (int m = 1; m < 16; m <<= 1) {
        s1 += __shfl_xor(s1, m, 64);
        s2 += __shfl_xor(s2, m, 64);
    }
    const float mu  = s1 * (1.f / 256.f);
    const float var = s2 * (1.f / 256.f) - mu * mu;
    const float inv = rsqrtf(var + 1e-5f);

    #pragma unroll
    for (int j = 0; j < 16; ++j) {
        const int d = s * 16 + j;
        h[j] = (h[j] - mu) * inv * lng[d] + lnb[d];
        if (RELU) h[j] = fmaxf(h[j], 0.f);
    }

    if (OUTB) {
        __hip_bfloat16* dst = outb + (size_t)node * 256 + s * 16;
        stb4(dst,      make_float4(h[0],  h[1],  h[2],  h[3]));
        stb4(dst + 4,  make_float4(h[4],  h[5],  h[6],  h[7]));
        stb4(dst + 8,  make_float4(h[8],  h[9],  h[10], h[11]));
        stb4(dst + 12, make_float4(h[12], h[13], h[14], h[15]));
    } else {
        float* dst = outf + (size_t)node * 256 + s * 16;
        #pragma unroll
        for (int c4 = 0; c4 < 4; ++c4)
            *reinterpret_cast<float4*>(dst + c4 * 4) =
                make_float4(h[c4 * 4], h[c4 * 4 + 1], h[c4 * 4 + 2], h[c4 * 4 + 3]);
    }
}

// ------------------------------ mean pool (two-stage) ----------------------
__global__ __launch_bounds__(256)
void pool_partial_kernel(const float* __restrict__ h, const int* __restrict__ gstart,
                         float* __restrict__ partial)
{
    const int s    = blockIdx.x;
    const int g    = blockIdx.y;
    const int tid  = threadIdx.x;
    const int quad = tid & 63;
    const int sub  = tid >> 6;

    const int beg = gstart[g];
    const int cnt = gstart[g + 1] - beg;

    f32x4 acc = {0.f, 0.f, 0.f, 0.f};
    for (int i = s * 4 + sub; i < cnt; i += 64) {
        const f32x4 v = *reinterpret_cast<const f32x4*>(
            h + (size_t)(beg + i) * 256 + quad * 4);
        acc += v;
    }

    __shared__ f32x4 sh[4][64];
    sh[sub][quad] = acc;
    __syncthreads();
    if (sub == 0) {
        const f32x4 r = sh[0][quad] + sh[1][quad] + sh[2][quad] + sh[3][quad];
        *reinterpret_cast<f32x4*>(partial + ((size_t)(g * 16 + s) * 64 + quad) * 4) = r;
    }
}

__global__ __launch_bounds__(256)
void pool_final_kernel(const float* __restrict__ partial, const int* __restrict__ gcount,
                       float* __restrict__ out)
{
    const int g = blockIdx.x;
    const int d = threadIdx.x;
    float sum = 0.f;
    #pragma unroll
    for (int s = 0; s < 16; ++s)
        sum += partial[(size_t)(g * 16 + s) * 256 + d];
    out[(size_t)g * 256 + d] = sum / (float)max(gcount[g], 1);
}

// ------------------------------- launcher ----------------------------------
extern "C" void kernel_launch(void* const* d_in, const int* in_sizes, int n_in,
                              void* d_out, int out_size, void* d_ws, size_t ws_size,
                              hipStream_t stream)
{
    const float* x     = (const float*)d_in[0];
    const int*   ei    = (const int*)d_in[1];
    const int*   batch = (const int*)d_in[2];
    const float* Wq0 = (const float*)d_in[3];  const float* bq0 = (const float*)d_in[4];
    const float* Wk0 = (const float*)d_in[5];  const float* bk0 = (const float*)d_in[6];
    const float* Wv0 = (const float*)d_in[7];  const float* bv0 = (const float*)d_in[8];
    const float* Ws0 = (const float*)d_in[9];  const float* bs0 = (const float*)d_in[10];
    const float* Wb0 = (const float*)d_in[11];
    const float* g0  = (const float*)d_in[12]; const float* b0  = (const float*)d_in[13];
    const float* Wq1 = (const float*)d_in[14]; const float* bq1 = (const float*)d_in[15];
    const float* Wk1 = (const float*)d_in[16]; const float* bk1 = (const float*)d_in[17];
    const float* Wv1 = (const float*)d_in[18]; const float* bv1 = (const float*)d_in[19];
    const float* Ws1 = (const float*)d_in[20]; const float* bs1 = (const float*)d_in[21];
    const float* Wb1 = (const float*)d_in[22];
    const float* g1  = (const float*)d_in[23]; const float* b1  = (const float*)d_in[24];

    const int N = in_sizes[0] / 256;
    const int E = in_sizes[1] / 2;
    const int G = 16;
    const size_t NM = (size_t)N * 256;

    __hip_bfloat16* bws = (__hip_bfloat16*)d_ws;
    __hip_bfloat16* xb  = bws;
    __hip_bfloat16* qb  = xb  + NM;
    __hip_bfloat16* rb  = qb  + NM;
    __hip_bfloat16* h0b = rb  + NM;
    __hip_bfloat16* wt  = h0b + NM;               // 8 * 65536 bf16
    unsigned char* kvb  = (unsigned char*)(wt + 8 * 65536);   // [N][512] fp8
    float* h1f     = (float*)(kvb + (size_t)N * 512);
    float* partial = h1f + NM;                    // 16*16*256 f32
    int* deg       = (int*)(partial + 16 * 16 * 256);
    int* row_start = deg + N;
    int* cursor    = row_start + N + 1;
    int* gcount    = cursor + N;
    int* gstart    = gcount + G;                  // 17
    int* csr_src   = gstart + 17;

    const int eb = (E + 255) / 256;
    const int nb = (N + 255) / 256;
    const int nf2b = (int)((NM / 4 + 255) / 256);

    const int zwords = 3 * N + G + 18;
    const int nz4    = (zwords + 3) / 4;
    const int nzb    = (nz4 + 255) / 256;

    prep_kernel<<<nf2b + 2048 + nzb, 256, 0, stream>>>(x, xb, nf2b,
        Wq0, Wk0, Wv0, Ws0, Wq1, Wk1, Wv1, Ws1, wt,
        (int4*)deg, nz4);

    build_kernel<<<eb + nb, 256, 0, stream>>>(ei, E, deg, eb, batch, N, gcount);
    scan_kernel<<<1, 1024, 0, stream>>>(deg, row_start, N, gcount, gstart);

    const int nrb   = (N + 127) / 128;
    const int ngemm = nrb * 8;
    const int agrid = (N + 1) / 2;

    // layer 0 (gemm grid carries the fill blocks)
    gemm_mfma_kernel<<<ngemm + eb, 256, 0, stream>>>(xb, N, wt,
        bq0, bk0, bv0, bs0,
        qb, kvb, kvb + 256, rb,
        256, 512, 512, 256,
        0, 1, 1, 0,
        ngemm, ei, E, E, row_start, cursor, csr_src);
    attn_kernel<2, true, true><<<agrid, 128, 0, stream>>>(
        qb, kvb, rb, Wb0, g0, b0, row_start, csr_src, h0b, nullptr, N, 0.125f);

    // layer 1 (no fill blocks)
    gemm_mfma_kernel<<<ngemm, 256, 0, stream>>>(h0b, N, wt + 4 * 65536,
        bq1, bk1, bv1, bs1,
        qb, kvb, kvb + 256, rb,
        256, 512, 512, 256,
        0, 1, 1, 0,
        ngemm, ei, E, 0, row_start, cursor, csr_src);
    attn_kernel<4, false, false><<<agrid, 128, 0, stream>>>(
        qb, kvb, rb, Wb1, g1, b1, row_start, csr_src, nullptr, h1f, N, 0.0625f);

    pool_partial_kernel<<<dim3(16, 16), 256, 0, stream>>>(h1f, gstart, partial);
    pool_final_kernel<<<16, 256, 0, stream>>>(partial, gcount, (float*)d_out);
}